// Round 1
// baseline (1025.301 us; speedup 1.0000x reference)
//
#include <hip/hip_runtime.h>

// DEQ MLP, B=1024, D_IN=512, D_H=1024, D_OUT=512. ALL I/O fp32.
// R12: fuse split-K reduction into the GEMM epilogue (last-block-reduces via
// device-scope atomic counter) and fuse all 5 prep kernels into one dispatch.
// Hot-path dispatches: 33 -> 15. Math is bitwise-identical to R11: same MFMA
// order per slice, same slice-order (0..3) summation, same bias/relu/cvt.

typedef _Float16 f16x8 __attribute__((ext_vector_type(8)));
typedef _Float16 f16x4v __attribute__((ext_vector_type(4)));
typedef float    f32x4 __attribute__((ext_vector_type(4)));

#define B_SZ 1024
#define DH   1024
#define PADK 72   // LDS row pitch in fp16 (144B = 9x16B): 16B-aligned rows,
                  // row-to-row bank shift of 4 -> 2 lanes/bank (free, m136)

// Partial P[s][M,N] = A[M, ks:ke] (fp16) * Bt[N, ks:ke]^T (fp16).
// 64x64 tile, BK=64, dbuf LDS, 4 waves each 32x32. blockIdx.z = split index.
// Epilogue: per-tile atomic counter; 4th-arriving block sums the 4 partials
// (slice order 0..3, == old reduce4), adds bias, RELU/cvt, stores output.
template<bool RELU, bool OUTF32>
__global__ __launch_bounds__(256, 4)
void gemm_sk64_fused(const _Float16* __restrict__ A,
                     const _Float16* __restrict__ Bt,
                     float* __restrict__ P,
                     const float* __restrict__ bias,
                     _Float16* __restrict__ o16,
                     float* __restrict__ o32,
                     unsigned* __restrict__ cnt,
                     int M, int N, int K)
{
  __shared__ alignas(16) _Float16 As[2][64 * PADK];
  __shared__ alignas(16) _Float16 Bs[2][64 * PADK];
  const int tid  = threadIdx.x;
  const int bm   = blockIdx.y * 64;
  const int bn   = blockIdx.x * 64;
  const int Ks   = K >> 2;                  // slice length (split=4)
  const int ks   = blockIdx.z * Ks;
  const int wave = tid >> 6;
  const int lane = tid & 63;
  const int quad = lane >> 4;
  const int l15  = lane & 15;
  const int wm   = (wave >> 1) * 32;
  const int wn   = (wave & 1) * 32;
  const int srow = tid >> 2;                // 64 rows x (4 threads x 2 chunks)
  const int c0   = (tid & 3) * 8;           // chunk cols: c0 and c0+32

  const _Float16* Ag = A  + (size_t)(bm + srow) * K + ks + c0;
  const _Float16* Bg = Bt + (size_t)(bn + srow) * K + ks + c0;
  const int sidx = srow * PADK + c0;

  f32x4 acc[2][2];
  #pragma unroll
  for (int i = 0; i < 2; i++)
    #pragma unroll
    for (int j = 0; j < 2; j++) { f32x4 z{0.f, 0.f, 0.f, 0.f}; acc[i][j] = z; }

  // stage iter 0 into buf 0
  int4 a0 = *(const int4*)(Ag);
  int4 a1 = *(const int4*)(Ag + 32);
  int4 b0 = *(const int4*)(Bg);
  int4 b1 = *(const int4*)(Bg + 32);
  *(int4*)&As[0][sidx]      = a0;
  *(int4*)&As[0][sidx + 32] = a1;
  *(int4*)&Bs[0][sidx]      = b0;
  *(int4*)&Bs[0][sidx + 32] = b1;
  __syncthreads();

  const int nIter = Ks >> 6;                // 4 (K=1024) or 2 (K=512)
  for (int it = 0; it < nIter; it++) {
    const int buf  = it & 1;
    const bool more = (it + 1 < nIter);
    if (more) {                             // prefetch next chunk (in flight)
      const int kn = (it + 1) << 6;
      a0 = *(const int4*)(Ag + kn);
      a1 = *(const int4*)(Ag + kn + 32);
      b0 = *(const int4*)(Bg + kn);
      b1 = *(const int4*)(Bg + kn + 32);
    }
    f16x8 af[2][2], bf[2][2];
    #pragma unroll
    for (int i = 0; i < 2; i++)
      #pragma unroll
      for (int k = 0; k < 2; k++) {
        af[i][k] = *(const f16x8*)&As[buf][(wm + i * 16 + l15) * PADK + k * 32 + quad * 8];
        bf[i][k] = *(const f16x8*)&Bs[buf][(wn + i * 16 + l15) * PADK + k * 32 + quad * 8];
      }
    #pragma unroll
    for (int k = 0; k < 2; k++) {           // k ascending == R11 order
      acc[0][0] = __builtin_amdgcn_mfma_f32_16x16x32_f16(af[0][k], bf[0][k], acc[0][0], 0, 0, 0);
      acc[0][1] = __builtin_amdgcn_mfma_f32_16x16x32_f16(af[0][k], bf[1][k], acc[0][1], 0, 0, 0);
      acc[1][0] = __builtin_amdgcn_mfma_f32_16x16x32_f16(af[1][k], bf[0][k], acc[1][0], 0, 0, 0);
      acc[1][1] = __builtin_amdgcn_mfma_f32_16x16x32_f16(af[1][k], bf[1][k], acc[1][1], 0, 0, 0);
    }
    if (more) {                             // write next into other buffer
      const int nb = buf ^ 1;
      *(int4*)&As[nb][sidx]      = a0;
      *(int4*)&As[nb][sidx + 32] = a1;
      *(int4*)&Bs[nb][sidx]      = b0;
      *(int4*)&Bs[nb][sidx + 32] = b1;
    }
    __syncthreads();                        // single barrier per iter
  }

  // C/D layout (m89-verified): col = lane&15, row = quad*4 + reg
  float* Pp = P + (size_t)blockIdx.z * M * N;
  #pragma unroll
  for (int j = 0; j < 2; j++) {
    const int col = bn + wn + j * 16 + l15;
    #pragma unroll
    for (int i = 0; i < 2; i++) {
      #pragma unroll
      for (int r = 0; r < 4; r++) {
        const int row = bm + wm + i * 16 + quad * 4 + r;
        Pp[(size_t)row * N + col] = acc[i][j][r];
      }
    }
  }

  // ---- fused split-K reduction: 4th-arriving block reduces this tile ----
  __syncthreads();                          // all waves' partial stores drained
  __shared__ unsigned arrive;
  if (tid == 0) {
    __threadfence();                        // release: partials visible device-wide
    arrive = atomicAdd(&cnt[blockIdx.y * gridDim.x + blockIdx.x], 1u);
  }
  __syncthreads();
  if (arrive == 3) {
    __threadfence();                        // acquire: see other slices' partials
    const size_t MN = (size_t)M * N;
    #pragma unroll
    for (int pass = 0; pass < 4; ++pass) {  // 64x64 tile = 4 x (16 rows x 64 cols)
      const int row = bm + pass * 16 + (tid >> 4);
      const int col = bn + (tid & 15) * 4;
      const size_t idx = (size_t)row * N + col;
      float4 v = *(const float4*)(P + idx);             // slice 0
      #pragma unroll
      for (int s = 1; s < 4; s++) {                     // slices 1..3 in order
        const float4 u = *(const float4*)(P + (size_t)s * MN + idx);
        v.x += u.x; v.y += u.y; v.z += u.z; v.w += u.w;
      }
      const float4 bb = *(const float4*)(bias + col);
      v.x += bb.x; v.y += bb.y; v.z += bb.z; v.w += bb.w;
      if (RELU) {
        v.x = fmaxf(v.x, 0.f); v.y = fmaxf(v.y, 0.f);
        v.z = fmaxf(v.z, 0.f); v.w = fmaxf(v.w, 0.f);
      }
      if (OUTF32) {
        *(float4*)(o32 + idx) = v;
      } else {
        f16x4v hv{(_Float16)v.x, (_Float16)v.y, (_Float16)v.z, (_Float16)v.w};
        *(f16x4v*)(o16 + idx) = hv;
      }
    }
  }
}

// One dispatch: x fp32->fp16 cvt (blocks 0..511, also zeroes split-K counters),
// then 32x32 transpose+cvt tiles for W_in / W1 / W2 / W_out (blocks 512..3583).
__global__ __launch_bounds__(256)
void prep_all(const float* __restrict__ x,     _Float16* __restrict__ xh,
              const float* __restrict__ W_in,  _Float16* __restrict__ WinT,
              const float* __restrict__ W1,    _Float16* __restrict__ W1T,
              const float* __restrict__ W2,    _Float16* __restrict__ W2T,
              const float* __restrict__ W_out, _Float16* __restrict__ WoutT,
              unsigned* __restrict__ cnt, int ncnt)
{
  int b = blockIdx.x;
  if (b < 512) {
    const int i = (b * 256 + threadIdx.x) * 4;          // 512*256*4 = 1024*512
    const float4 v = *(const float4*)(x + i);
    f16x4v hv{(_Float16)v.x, (_Float16)v.y, (_Float16)v.z, (_Float16)v.w};
    *(f16x4v*)(xh + i) = hv;
    const int ci = b * 256 + threadIdx.x;
    if (ci < ncnt) cnt[ci] = 0;                         // zero split-K counters
    return;
  }
  b -= 512;
  const float* src; _Float16* dst; int R, C, bx, by;
  if (b < 512)       { src = W_in;  dst = WinT;  R = 512;  C = 1024; bx = b & 31; by = b >> 5; }
  else if (b < 1536) { b -= 512;  src = W1;    dst = W1T;   R = 1024; C = 1024; bx = b & 31; by = b >> 5; }
  else if (b < 2560) { b -= 1536; src = W2;    dst = W2T;   R = 1024; C = 1024; bx = b & 31; by = b >> 5; }
  else               { b -= 2560; src = W_out; dst = WoutT; R = 1024; C = 512;  bx = b & 15; by = b >> 4; }

  __shared__ float t[32][33];
  const int tx = threadIdx.x & 31;
  const int ty = threadIdx.x >> 5;
  const int c0 = bx * 32;
  const int r0 = by * 32;
  #pragma unroll
  for (int i = 0; i < 32; i += 8)
    t[ty + i][tx] = src[(size_t)(r0 + ty + i) * C + c0 + tx];
  __syncthreads();
  #pragma unroll
  for (int i = 0; i < 32; i += 8)
    dst[(size_t)(c0 + ty + i) * R + r0 + tx] = (_Float16)t[tx][ty + i];
}

extern "C" void kernel_launch(void* const* d_in, const int* in_sizes, int n_in,
                              void* d_out, int out_size, void* d_ws, size_t ws_size,
                              hipStream_t stream) {
  (void)in_sizes; (void)n_in; (void)out_size; (void)ws_size;
  const float* x     = (const float*)d_in[0];
  const float* W_in  = (const float*)d_in[1];
  const float* b_in  = (const float*)d_in[2];
  const float* W1    = (const float*)d_in[3];
  const float* b1    = (const float*)d_in[4];
  const float* W2    = (const float*)d_in[5];
  const float* b2    = (const float*)d_in[6];
  const float* W_out = (const float*)d_in[7];
  const float* b_out = (const float*)d_in[8];
  float* out = (float*)d_out;

  const size_t BD = (size_t)B_SZ * DH;   // 1M
  char* p = (char*)d_ws;
  _Float16* xh    = (_Float16*)p; p += (size_t)1024 * 512 * 2;
  _Float16* WinT  = (_Float16*)p; p += (size_t)1024 * 512 * 2;
  _Float16* W1T   = (_Float16*)p; p += (size_t)DH * DH * 2;
  _Float16* W2T   = (_Float16*)p; p += (size_t)DH * DH * 2;
  _Float16* WoutT = (_Float16*)p; p += (size_t)512 * 1024 * 2;
  _Float16* za    = (_Float16*)p; p += BD * 2;
  _Float16* zb    = (_Float16*)p; p += BD * 2;
  _Float16* h     = (_Float16*)p; p += BD * 2;
  float*    P     = (float*)p;    p += (size_t)4 * 1024 * 1024 * 4;  // 16MB
  unsigned* cnt   = (unsigned*)p;                                    // 14*256*4B

  const int NCNT = 14 * 256;
  dim3 blk(256);
  prep_all<<<dim3(3584), blk, 0, stream>>>(x, xh, W_in, WinT, W1, W1T,
                                           W2, W2T, W_out, WoutT, cnt, NCNT);

  const dim3 gSK(16, 16, 4);       // 1024x1024 out, split-K=4

  // z0 = x @ W_in + b_in
  gemm_sk64_fused<false, false><<<gSK, blk, 0, stream>>>(
      xh, WinT, P, b_in, za, nullptr, cnt + 0 * 256, 1024, 1024, 512);

  // Picard: z <- relu(z@W1+b1)@W2+b2, 6 iterations
  _Float16* zc = za;
  _Float16* zn = zb;
  int g = 1;
  for (int it = 0; it < 6; it++) {
    gemm_sk64_fused<true, false><<<gSK, blk, 0, stream>>>(
        zc, W1T, P, b1, h, nullptr, cnt + g * 256, 1024, 1024, 1024); g++;
    gemm_sk64_fused<false, false><<<gSK, blk, 0, stream>>>(
        h, W2T, P, b2, zn, nullptr, cnt + g * 256, 1024, 1024, 1024); g++;
    _Float16* t = zc; zc = zn; zn = t;
  }

  // out = z* @ W_out + b_out (fp32)
  gemm_sk64_fused<false, true><<<dim3(8, 16, 4), blk, 0, stream>>>(
      zc, WoutT, P, b_out, nullptr, out, cnt + g * 256, 1024, 512, 1024);
}

// Round 2
// 217.816 us; speedup vs baseline: 4.7072x; 4.7072x over previous
//
#include <hip/hip_runtime.h>

// DEQ MLP, B=1024, D_IN=512, D_H=1024, D_OUT=512. ALL I/O fp32.
// R13: NO split-K, NO cross-block sync (R12's device-scope fences caused
// full-L2 writebacks per block -> 4x regression). Each block computes a
// 64x32 output tile over the FULL K and applies bias/ReLU/cvt in the
// epilogue. 512 blocks (2/CU) for 1024-wide outputs. Dispatches: 15 total
// (1 fused prep + 14 GEMMs). Inner loop structure identical to R11
// (dbuf LDS, 1 barrier/iter, register prefetch, PADK=72).

typedef _Float16 f16x8 __attribute__((ext_vector_type(8)));
typedef _Float16 f16x4v __attribute__((ext_vector_type(4)));
typedef float    f32x4 __attribute__((ext_vector_type(4)));

#define B_SZ 1024
#define DH   1024
#define PADK 72   // LDS row pitch in fp16 (144B = 9x16B): 16B-aligned rows,
                  // row-to-row bank shift of 4 -> 2 lanes/bank (free, m136)

// out[M,N] = act(A[M,K] (fp16) * Bt[N,K]^T (fp16) + bias).
// 64x32 tile, BK=64, dbuf LDS, 4 waves each 16x32. Full K in-block.
template<bool RELU, bool OUTF32>
__global__ __launch_bounds__(256, 2)
void gemm_full(const _Float16* __restrict__ A,
               const _Float16* __restrict__ Bt,
               const float* __restrict__ bias,
               _Float16* __restrict__ o16,
               float* __restrict__ o32,
               int M, int N, int K)
{
  __shared__ alignas(16) _Float16 As[2][64 * PADK];
  __shared__ alignas(16) _Float16 Bs[2][32 * PADK];
  const int tid  = threadIdx.x;
  const int bm   = blockIdx.y * 64;
  const int bn   = blockIdx.x * 32;
  const int wave = tid >> 6;
  const int lane = tid & 63;
  const int quad = lane >> 4;
  const int l15  = lane & 15;
  const int wm   = wave * 16;              // wave covers rows wm..wm+15, all 32 cols

  // A staging: 64 rows x (4 threads x 2 chunks of 8 fp16)
  const int srowA = tid >> 2;
  const int c0A   = (tid & 3) * 8;         // chunks at c0A and c0A+32
  // B staging: 32 rows x (8 threads x 1 chunk of 8 fp16)
  const int srowB = tid >> 3;
  const int c0B   = (tid & 7) * 8;

  const _Float16* Ag = A  + (size_t)(bm + srowA) * K + c0A;
  const _Float16* Bg = Bt + (size_t)(bn + srowB) * K + c0B;
  const int saA = srowA * PADK + c0A;
  const int saB = srowB * PADK + c0B;

  f32x4 acc[2];
  { f32x4 z{0.f, 0.f, 0.f, 0.f}; acc[0] = z; acc[1] = z; }

  // stage iter 0 into buf 0
  int4 a0 = *(const int4*)(Ag);
  int4 a1 = *(const int4*)(Ag + 32);
  int4 b0 = *(const int4*)(Bg);
  *(int4*)&As[0][saA]      = a0;
  *(int4*)&As[0][saA + 32] = a1;
  *(int4*)&Bs[0][saB]      = b0;
  __syncthreads();

  const int nIter = K >> 6;                // 16 (K=1024) or 8 (K=512)
  for (int it = 0; it < nIter; it++) {
    const int buf  = it & 1;
    const bool more = (it + 1 < nIter);
    if (more) {                            // prefetch next chunk (in flight)
      const int kn = (it + 1) << 6;
      a0 = *(const int4*)(Ag + kn);
      a1 = *(const int4*)(Ag + kn + 32);
      b0 = *(const int4*)(Bg + kn);
    }
    f16x8 af[2], bf[2][2];
    #pragma unroll
    for (int k = 0; k < 2; k++) {
      af[k]    = *(const f16x8*)&As[buf][(wm + l15) * PADK + k * 32 + quad * 8];
      bf[0][k] = *(const f16x8*)&Bs[buf][(l15)      * PADK + k * 32 + quad * 8];
      bf[1][k] = *(const f16x8*)&Bs[buf][(16 + l15) * PADK + k * 32 + quad * 8];
    }
    #pragma unroll
    for (int k = 0; k < 2; k++) {          // k ascending
      acc[0] = __builtin_amdgcn_mfma_f32_16x16x32_f16(af[k], bf[0][k], acc[0], 0, 0, 0);
      acc[1] = __builtin_amdgcn_mfma_f32_16x16x32_f16(af[k], bf[1][k], acc[1], 0, 0, 0);
    }
    if (more) {                            // write next into other buffer
      const int nb = buf ^ 1;
      *(int4*)&As[nb][saA]      = a0;
      *(int4*)&As[nb][saA + 32] = a1;
      *(int4*)&Bs[nb][saB]      = b0;
    }
    __syncthreads();                       // single barrier per iter
  }

  // Epilogue: bias + act + store. C/D layout (m89-verified):
  // col = lane&15, row = quad*4 + reg
  #pragma unroll
  for (int j = 0; j < 2; j++) {
    const int col = bn + j * 16 + l15;
    const float bb = bias[col];
    #pragma unroll
    for (int r = 0; r < 4; r++) {
      const int row = bm + wm + quad * 4 + r;
      float v = acc[j][r] + bb;
      if (RELU) v = fmaxf(v, 0.f);
      if (OUTF32) o32[(size_t)row * N + col] = v;
      else        o16[(size_t)row * N + col] = (_Float16)v;
    }
  }
}

// One dispatch: x fp32->fp16 cvt (blocks 0..511), then 32x32 transpose+cvt
// tiles for W_in / W1 / W2 / W_out (blocks 512..3583).
__global__ __launch_bounds__(256)
void prep_all(const float* __restrict__ x,     _Float16* __restrict__ xh,
              const float* __restrict__ W_in,  _Float16* __restrict__ WinT,
              const float* __restrict__ W1,    _Float16* __restrict__ W1T,
              const float* __restrict__ W2,    _Float16* __restrict__ W2T,
              const float* __restrict__ W_out, _Float16* __restrict__ WoutT)
{
  int b = blockIdx.x;
  if (b < 512) {
    const int i = (b * 256 + threadIdx.x) * 4;          // 512*256*4 = 1024*512
    const float4 v = *(const float4*)(x + i);
    f16x4v hv{(_Float16)v.x, (_Float16)v.y, (_Float16)v.z, (_Float16)v.w};
    *(f16x4v*)(xh + i) = hv;
    return;
  }
  b -= 512;
  const float* src; _Float16* dst; int R, C, bx, by;
  if (b < 512)       { src = W_in;  dst = WinT;  R = 512;  C = 1024; bx = b & 31; by = b >> 5; }
  else if (b < 1536) { b -= 512;  src = W1;    dst = W1T;   R = 1024; C = 1024; bx = b & 31; by = b >> 5; }
  else if (b < 2560) { b -= 1536; src = W2;    dst = W2T;   R = 1024; C = 1024; bx = b & 31; by = b >> 5; }
  else               { b -= 2560; src = W_out; dst = WoutT; R = 1024; C = 512;  bx = b & 15; by = b >> 4; }

  __shared__ float t[32][33];
  const int tx = threadIdx.x & 31;
  const int ty = threadIdx.x >> 5;
  const int c0 = bx * 32;
  const int r0 = by * 32;
  #pragma unroll
  for (int i = 0; i < 32; i += 8)
    t[ty + i][tx] = src[(size_t)(r0 + ty + i) * C + c0 + tx];
  __syncthreads();
  #pragma unroll
  for (int i = 0; i < 32; i += 8)
    dst[(size_t)(c0 + ty + i) * R + r0 + tx] = (_Float16)t[tx][ty + i];
}

extern "C" void kernel_launch(void* const* d_in, const int* in_sizes, int n_in,
                              void* d_out, int out_size, void* d_ws, size_t ws_size,
                              hipStream_t stream) {
  (void)in_sizes; (void)n_in; (void)out_size; (void)ws_size;
  const float* x     = (const float*)d_in[0];
  const float* W_in  = (const float*)d_in[1];
  const float* b_in  = (const float*)d_in[2];
  const float* W1    = (const float*)d_in[3];
  const float* b1    = (const float*)d_in[4];
  const float* W2    = (const float*)d_in[5];
  const float* b2    = (const float*)d_in[6];
  const float* W_out = (const float*)d_in[7];
  const float* b_out = (const float*)d_in[8];
  float* out = (float*)d_out;

  const size_t BD = (size_t)B_SZ * DH;   // 1M
  char* p = (char*)d_ws;
  _Float16* xh    = (_Float16*)p; p += (size_t)1024 * 512 * 2;
  _Float16* WinT  = (_Float16*)p; p += (size_t)1024 * 512 * 2;
  _Float16* W1T   = (_Float16*)p; p += (size_t)DH * DH * 2;
  _Float16* W2T   = (_Float16*)p; p += (size_t)DH * DH * 2;
  _Float16* WoutT = (_Float16*)p; p += (size_t)512 * 1024 * 2;
  _Float16* za    = (_Float16*)p; p += BD * 2;
  _Float16* zb    = (_Float16*)p; p += BD * 2;
  _Float16* h     = (_Float16*)p; p += BD * 2;

  dim3 blk(256);
  prep_all<<<dim3(3584), blk, 0, stream>>>(x, xh, W_in, WinT, W1, W1T,
                                           W2, W2T, W_out, WoutT);

  const dim3 g1024(32, 16);        // 1024x1024 out: 64x32 tiles, 512 blocks
  const dim3 g512 (16, 16);        // 1024x512  out: 256 blocks

  // z0 = x @ W_in + b_in
  gemm_full<false, false><<<g1024, blk, 0, stream>>>(
      xh, WinT, b_in, za, nullptr, 1024, 1024, 512);

  // Picard: z <- relu(z@W1+b1)@W2+b2, 6 iterations
  _Float16* zc = za;
  _Float16* zn = zb;
  for (int it = 0; it < 6; it++) {
    gemm_full<true, false><<<g1024, blk, 0, stream>>>(
        zc, W1T, b1, h, nullptr, 1024, 1024, 1024);
    gemm_full<false, false><<<g1024, blk, 0, stream>>>(
        h, W2T, b2, zn, nullptr, 1024, 1024, 1024);
    _Float16* t = zc; zc = zn; zn = t;
  }

  // out = z* @ W_out + b_out (fp32)
  gemm_full<false, true><<<g512, blk, 0, stream>>>(
      zc, WoutT, b_out, nullptr, out, 1024, 512, 1024);
}